// Round 9
// baseline (148.895 us; speedup 1.0000x reference)
//
#include <hip/hip_runtime.h>
#include <math.h>

#define BB 64
#define SS 8192
#define IN_DIM 512
#define OUT_DIM 128
#define DVV 128
#define CHUNK 256
#define NCHUNK (SS / CHUNK)   // 32

// Kernel 1: qt[b] = (Wk @ (q[b] @ Wq)) / sqrt(OUT_DIM)   (512 threads, 4-way split-K)
__global__ __launch_bounds__(512) void qt_kernel(const float* __restrict__ q,
                          const float* __restrict__ Wq,
                          const float* __restrict__ Wk,
                          float* __restrict__ qt) {
    int b = blockIdx.x;
    int t = threadIdx.x;
    int e = t & 127;          // output index
    int h = t >> 7;           // split 0..3
    __shared__ float part[4][OUT_DIM];
    __shared__ float qs[OUT_DIM];

    const float* qb = q + (size_t)b * IN_DIM;
    float acc = 0.f;
    for (int i = h * (IN_DIM / 4); i < (h + 1) * (IN_DIM / 4); ++i)
        acc = fmaf(qb[i], Wq[(size_t)i * OUT_DIM + e], acc);
    part[h][e] = acc;
    __syncthreads();
    if (h == 0) qs[e] = part[0][e] + part[1][e] + part[2][e] + part[3][e];
    __syncthreads();

    float a2 = 0.f;
    const float* wkrow = Wk + (size_t)e * OUT_DIM;
    for (int i = h * (OUT_DIM / 4); i < (h + 1) * (OUT_DIM / 4); ++i)
        a2 = fmaf(wkrow[i], qs[i], a2);
    part[h][e] = a2;
    __syncthreads();
    if (h == 0)
        qt[(size_t)b * OUT_DIM + e] =
            (part[0][e] + part[1][e] + part[2][e] + part[3][e]) * 0.08838834764831845f;
}

// Kernel 2: R0 structure with deep ILP — 4 independent float4 loads in
// flight per thread in both streaming phases; __launch_bounds__(256,4)
// gives the allocator ~128 VGPRs so it doesn't waitcnt after each load.
// (R7 bug fixed: 256 threads own exactly one sc[] entry each — no t+128.)
__global__ __launch_bounds__(256, 4) void partial_kernel(
    const float* __restrict__ k, const float* __restrict__ v,
    const float* __restrict__ qt, float* __restrict__ ml,
    float* __restrict__ ctx) {
    int blk = blockIdx.x;
    int b = blk / NCHUNK;
    int c = blk % NCHUNK;
    int s0 = c * CHUNK;
    int t = threadIdx.x;
    int wave = t >> 6, lane = t & 63, half = lane >> 5, l32 = lane & 31;

    __shared__ float4 qts4[OUT_DIM / 4];
    __shared__ float sc[CHUNK];
    __shared__ float4 red[256];
    __shared__ float wred[4];

    if (t < OUT_DIM / 4)
        qts4[t] = ((const float4*)(qt + (size_t)b * OUT_DIM))[t];
    __syncthreads();

    // ---- Phase A: scores; 8 rows/block/iter, unrolled 4 rows per thread ----
    const float4* k4 = (const float4*)(k + (size_t)b * SS * OUT_DIM);
    float4 qv = qts4[l32];
    int r0 = wave * 2 + half;                 // 0..7
    const float4* kbase = k4 + (size_t)(s0 + r0) * (OUT_DIM / 4) + l32;
    #pragma unroll
    for (int j = 0; j < CHUNK / 8; j += 4) {
        // 4 independent loads issued before any consumer
        float4 kv0 = kbase[(size_t)(j + 0) * 8 * (OUT_DIM / 4)];
        float4 kv1 = kbase[(size_t)(j + 1) * 8 * (OUT_DIM / 4)];
        float4 kv2 = kbase[(size_t)(j + 2) * 8 * (OUT_DIM / 4)];
        float4 kv3 = kbase[(size_t)(j + 3) * 8 * (OUT_DIM / 4)];
        float p0 = kv0.x * qv.x + kv0.y * qv.y + kv0.z * qv.z + kv0.w * qv.w;
        float p1 = kv1.x * qv.x + kv1.y * qv.y + kv1.z * qv.z + kv1.w * qv.w;
        float p2 = kv2.x * qv.x + kv2.y * qv.y + kv2.z * qv.z + kv2.w * qv.w;
        float p3 = kv3.x * qv.x + kv3.y * qv.y + kv3.z * qv.z + kv3.w * qv.w;
        #pragma unroll
        for (int d = 1; d < 32; d <<= 1) {
            p0 += __shfl_xor(p0, d);
            p1 += __shfl_xor(p1, d);
            p2 += __shfl_xor(p2, d);
            p3 += __shfl_xor(p3, d);
        }
        if (l32 == 0) {
            sc[r0 + 8 * (j + 0)] = p0;
            sc[r0 + 8 * (j + 1)] = p1;
            sc[r0 + 8 * (j + 2)] = p2;
            sc[r0 + 8 * (j + 3)] = p3;
        }
    }
    __syncthreads();

    // ---- chunk max (each of 256 threads owns one score) ----
    float m = sc[t];
    for (int d = 1; d < 64; d <<= 1) m = fmaxf(m, __shfl_xor(m, d));
    if (lane == 0) wred[wave] = m;
    __syncthreads();
    m = fmaxf(fmaxf(wred[0], wred[1]), fmaxf(wred[2], wred[3]));
    __syncthreads();  // protect wred reuse

    // ---- exp + chunk sum ----
    float e0 = __expf(sc[t] - m);
    sc[t] = e0;
    float lsum = e0;
    for (int d = 1; d < 64; d <<= 1) lsum += __shfl_xor(lsum, d);
    if (lane == 0) wred[wave] = lsum;
    __syncthreads();  // also makes sc[] weights visible to all
    lsum = wred[0] + wred[1] + wred[2] + wred[3];

    // ---- Phase B: partial context; unrolled 4 rows per thread ----
    int col = t & 31;   // float4 column
    int rg = t >> 5;    // row group 0..7
    const float4* v4 = (const float4*)(v + (size_t)b * SS * DVV);
    const float4* vbase = v4 + (size_t)(s0 + rg) * (DVV / 4) + col;
    float4 acc = make_float4(0.f, 0.f, 0.f, 0.f);
    #pragma unroll
    for (int j = 0; j < CHUNK / 8; j += 4) {
        float4 vv0 = vbase[(size_t)(j + 0) * 8 * (DVV / 4)];
        float4 vv1 = vbase[(size_t)(j + 1) * 8 * (DVV / 4)];
        float4 vv2 = vbase[(size_t)(j + 2) * 8 * (DVV / 4)];
        float4 vv3 = vbase[(size_t)(j + 3) * 8 * (DVV / 4)];
        float p0 = sc[rg + 8 * (j + 0)];
        float p1 = sc[rg + 8 * (j + 1)];
        float p2 = sc[rg + 8 * (j + 2)];
        float p3 = sc[rg + 8 * (j + 3)];
        acc.x = fmaf(p0, vv0.x, acc.x); acc.y = fmaf(p0, vv0.y, acc.y);
        acc.z = fmaf(p0, vv0.z, acc.z); acc.w = fmaf(p0, vv0.w, acc.w);
        acc.x = fmaf(p1, vv1.x, acc.x); acc.y = fmaf(p1, vv1.y, acc.y);
        acc.z = fmaf(p1, vv1.z, acc.z); acc.w = fmaf(p1, vv1.w, acc.w);
        acc.x = fmaf(p2, vv2.x, acc.x); acc.y = fmaf(p2, vv2.y, acc.y);
        acc.z = fmaf(p2, vv2.z, acc.z); acc.w = fmaf(p2, vv2.w, acc.w);
        acc.x = fmaf(p3, vv3.x, acc.x); acc.y = fmaf(p3, vv3.y, acc.y);
        acc.z = fmaf(p3, vv3.z, acc.z); acc.w = fmaf(p3, vv3.w, acc.w);
    }
    red[t] = acc;
    __syncthreads();
    for (int off = 128; off >= 32; off >>= 1) {
        if (t < off) {
            float4 o = red[t + off];
            red[t].x += o.x; red[t].y += o.y;
            red[t].z += o.z; red[t].w += o.w;
        }
        __syncthreads();
    }
    if (t < 32)
        ((float4*)(ctx + ((size_t)(b * NCHUNK + c)) * DVV))[t] = red[t];
    if (t == 0) {
        ml[(b * NCHUNK + c) * 2 + 0] = m;
        ml[(b * NCHUNK + c) * 2 + 1] = lsum;
    }
}

// Kernel 3: merge chunk partials with max-rescaling.
__global__ void combine_kernel(const float* __restrict__ ml,
                               const float* __restrict__ ctx,
                               float* __restrict__ out) {
    int b = blockIdx.x;
    int t = threadIdx.x;  // 128
    __shared__ float ms, ls;
    float m = -INFINITY;
    if (t < NCHUNK) m = ml[(b * NCHUNK + t) * 2];
    for (int d = 1; d < 32; d <<= 1) m = fmaxf(m, __shfl_xor(m, d));
    if (t == 0) ms = m;
    __syncthreads();
    m = ms;
    float l = 0.f;
    if (t < NCHUNK)
        l = ml[(b * NCHUNK + t) * 2 + 1] * __expf(ml[(b * NCHUNK + t) * 2] - m);
    for (int d = 1; d < 32; d <<= 1) l += __shfl_xor(l, d);
    if (t == 0) ls = l;
    __syncthreads();
    l = ls;
    float acc = 0.f;
    for (int c2 = 0; c2 < NCHUNK; ++c2) {
        float w = __expf(ml[(b * NCHUNK + c2) * 2] - m);
        acc = fmaf(ctx[((size_t)(b * NCHUNK + c2)) * DVV + t], w, acc);
    }
    out[(size_t)b * DVV + t] = acc / l;
}

extern "C" void kernel_launch(void* const* d_in, const int* in_sizes, int n_in,
                              void* d_out, int out_size, void* d_ws, size_t ws_size,
                              hipStream_t stream) {
    const float* k  = (const float*)d_in[0];
    const float* q  = (const float*)d_in[1];
    const float* v  = (const float*)d_in[2];
    const float* Wk = (const float*)d_in[3];
    const float* Wq = (const float*)d_in[4];
    float* out = (float*)d_out;

    float* qt  = (float*)d_ws;                 // B*128 floats
    float* ml  = qt + BB * OUT_DIM;            // B*NCHUNK*2 floats
    float* ctx = ml + BB * NCHUNK * 2;         // B*NCHUNK*128 floats (~1 MB total)

    qt_kernel<<<BB, 512, 0, stream>>>(q, Wq, Wk, qt);
    partial_kernel<<<BB * NCHUNK, 256, 0, stream>>>(k, v, qt, ml, ctx);
    combine_kernel<<<BB, DVV, 0, stream>>>(ml, ctx, out);
}